// Round 4
// baseline (726.559 us; speedup 1.0000x reference)
//
#include <hip/hip_runtime.h>
#include <stdint.h>

// Problem constants (fixed by the reference)
#define CHARS   10000
#define KPAD    10240   // K padded to multiple of 64
#define HIDDEN  1024
#define OUTPUT  100
#define OPAD    128     // padded output cols for coalesced W2T
#define BATCH   4096
#define MAXLEN  2048

typedef __bf16 bf16_t;
typedef __bf16 bf16x8 __attribute__((ext_vector_type(8)));
typedef float  f32x4  __attribute__((ext_vector_type(4)));

// Raw barrier: LDS visibility only (lgkmcnt(0)), NO vmcnt drain.
// __syncthreads would drain vmcnt(0), killing cross-barrier load pipelining.
// "memory" clobber pins ds/global op ordering across the barrier.
#define BARRIER() asm volatile("s_waitcnt lgkmcnt(0)\n\ts_barrier" ::: "memory")

// ---------------------------------------------------------------------------
// W1 (HIDDEN x CHARS fp32) -> W1b (HIDDEN x KPAD bf16), zero-padded cols.
// ---------------------------------------------------------------------------
__global__ void k_w1bf16(const float* __restrict__ W1, bf16_t* __restrict__ W1b) {
    int c = blockIdx.x * 256 + threadIdx.x;   // 0..KPAD-1
    int h = blockIdx.y;                       // 0..HIDDEN-1
    float v = (c < CHARS) ? W1[(size_t)h * CHARS + c] : 0.0f;
    W1b[(size_t)h * KPAD + c] = (bf16_t)v;
}

// ---------------------------------------------------------------------------
// W2 (OUTPUT x HIDDEN fp32) -> W2T (HIDDEN x OPAD fp32), zero-padded cols.
// ---------------------------------------------------------------------------
__global__ void k_w2t(const float* __restrict__ W2, float* __restrict__ W2T) {
    int o = threadIdx.x;      // 0..127
    int k = blockIdx.x;       // 0..1023
    W2T[(size_t)k * OPAD + o] = (o < OUTPUT) ? W2[(size_t)o * HIDDEN + k] : 0.0f;
}

// ---------------------------------------------------------------------------
// hid pre-init with b1 (split-K GEMM atomically accumulates on top)
// ---------------------------------------------------------------------------
__global__ void k_hidinit(const float* __restrict__ b1, float* __restrict__ hid) {
    int h = blockIdx.y * 256 + threadIdx.x;   // 0..1023
    hid[(size_t)blockIdx.x * HIDDEN + h] = b1[h];
}

// ---------------------------------------------------------------------------
// Per-row histogram: one block per batch row. 40KB LDS uint32 counts.
// ---------------------------------------------------------------------------
__global__ void k_hist(const int* __restrict__ words, bf16_t* __restrict__ hist,
                       int rowStart) {
    __shared__ uint32_t h[KPAD];              // 40 KB
    const int tid = threadIdx.x;
    for (int i = tid; i < KPAD; i += 256) h[i] = 0u;
    __syncthreads();
    const int* w = words + (size_t)(rowStart + blockIdx.x) * MAXLEN;
    for (int i = tid; i < MAXLEN; i += 256)
        atomicAdd(&h[w[i]], 1u);
    __syncthreads();
    bf16_t* dst = hist + (size_t)blockIdx.x * KPAD;
    for (int i = tid; i < KPAD; i += 256)
        dst[i] = (bf16_t)(float)h[i];
}

// ---------------------------------------------------------------------------
// GEMM helpers
// ---------------------------------------------------------------------------
__device__ __forceinline__ void load_set(const bf16_t* Ag, const bf16_t* Bg,
                                         long k, bf16x8* rA, bf16x8* rB) {
#pragma unroll
    for (int i = 0; i < 4; ++i) {
        rA[i] = *(const bf16x8*)(Ag + (size_t)i * 32 * KPAD + k);
        rB[i] = *(const bf16x8*)(Bg + (size_t)i * 32 * KPAD + k);
    }
}

__device__ __forceinline__ void stage_writes(bf16_t* Awr, bf16_t* Bwr,
                                             const bf16x8* rA, const bf16x8* rB) {
#pragma unroll
    for (int i = 0; i < 4; ++i) {
        *(bf16x8*)(Awr + i * 32 * 64) = rA[i];
        *(bf16x8*)(Bwr + i * 32 * 64) = rB[i];
    }
}

__device__ __forceinline__ void compute_step(const bf16_t* As, const bf16_t* Bs,
                                             int wm, int wn, int fr, int qd,
                                             f32x4 acc[4][4]) {
#pragma unroll
    for (int kk = 0; kk < 64; kk += 32) {
        const int gc = (kk >> 3) + qd;        // global 16B-chunk index 0..7
        bf16x8 af[4], bq[4];
#pragma unroll
        for (int i = 0; i < 4; ++i) {
            const int R = wm + i * 16 + fr;
            af[i] = *(const bf16x8*)(As + R * 64 + ((gc ^ (R & 7)) * 8));
        }
#pragma unroll
        for (int j = 0; j < 4; ++j) {
            const int R = wn + j * 16 + fr;
            bq[j] = *(const bf16x8*)(Bs + R * 64 + ((gc ^ (R & 7)) * 8));
        }
#pragma unroll
        for (int i = 0; i < 4; ++i)
#pragma unroll
            for (int j = 0; j < 4; ++j)
                acc[i][j] = __builtin_amdgcn_mfma_f32_16x16x32_bf16(
                    af[i], bq[j], acc[i][j], 0, 0, 0);
    }
}

// ---------------------------------------------------------------------------
// bf16 MFMA GEMM: 128x128 tile, BK=64, XOR-swizzled LDS (conflict-free,
// measured 0 in R2), raw lgkm-only barriers + 2-deep register prefetch:
// global loads issued ~2 ksteps before consumption fly through barriers
// untouched (no vmcnt(0) drain), hiding L3/HBM latency.
// Split-K over blockIdx.z -> fp32 atomicAdd into pre-initialized hid.
// ---------------------------------------------------------------------------
__global__ void __launch_bounds__(256, 4)
k_gemm(const bf16_t* __restrict__ A, const bf16_t* __restrict__ Bt,
       float* __restrict__ hid, int ksteps_per_slice) {
    __shared__ __attribute__((aligned(16))) bf16_t As[128 * 64];  // 16 KB
    __shared__ __attribute__((aligned(16))) bf16_t Bs[128 * 64];  // 16 KB

    const int tid  = threadIdx.x;
    const int lane = tid & 63;
    const int wave = tid >> 6;
    const int m0 = blockIdx.x * 128;
    const int n0 = blockIdx.y * 128;
    const long kbeg = (long)blockIdx.z * ksteps_per_slice * 64;
    const long kend = kbeg + (long)ksteps_per_slice * 64;

    // staging map: thread covers rows srow+32i, global 16B-chunk g=tid&7.
    // LDS chunk c of row r holds global chunk c ^ (r&7)  (r&7 == srow&7).
    const int srow = tid >> 3;            // 0..31
    const int g    = tid & 7;
    const int wch  = g ^ (srow & 7);
    const bf16_t* Ag = A  + (size_t)(m0 + srow) * KPAD + g * 8;
    const bf16_t* Bg = Bt + (size_t)(n0 + srow) * KPAD + g * 8;
    bf16_t* Awr = As + srow * 64 + wch * 8;
    bf16_t* Bwr = Bs + srow * 64 + wch * 8;

    f32x4 acc[4][4] = {};
    const int wm = (wave & 1) * 64;       // wave's 64x64 sub-tile
    const int wn = (wave >> 1) * 64;
    const int fr = lane & 15;
    const int qd = lane >> 4;

    // prologue: 2 k-steps in flight
    bf16x8 r0A[4], r0B[4], r1A[4], r1B[4];
    load_set(Ag, Bg, kbeg,      r0A, r0B);
    load_set(Ag, Bg, kbeg + 64, r1A, r1B);

    for (long k = kbeg; k < kend; k += 128) {
        // even k-step (r0)
        stage_writes(Awr, Bwr, r0A, r0B);            // waits r0 loads (vmcnt(8))
        if (k + 128 < kend) load_set(Ag, Bg, k + 128, r0A, r0B);
        BARRIER();                                   // lgkm(0) only
        compute_step(As, Bs, wm, wn, fr, qd, acc);
        BARRIER();
        // odd k-step (r1)
        stage_writes(Awr, Bwr, r1A, r1B);
        if (k + 192 < kend) load_set(Ag, Bg, k + 192, r1A, r1B);
        BARRIER();
        compute_step(As, Bs, wm, wn, fr, qd, acc);
        BARRIER();
    }

    // epilogue: C/D layout col=lane&15, row=(lane>>4)*4+reg  [guide §3, m89]
    const int er = (lane >> 4) * 4;
    const int ec = lane & 15;
#pragma unroll
    for (int i = 0; i < 4; ++i) {
#pragma unroll
        for (int j = 0; j < 4; ++j) {
            float* dst = hid + (size_t)(m0 + wm + i * 16 + er) * HIDDEN
                             + (n0 + wn + j * 16 + ec);
#pragma unroll
            for (int r = 0; r < 4; ++r)
                atomicAdd(dst + (size_t)r * HIDDEN, acc[i][j][r]);
        }
    }
}

// ---------------------------------------------------------------------------
// out[b,o] = sum_k hid[b,k] * W2T[k,o] + b2[o]
// ---------------------------------------------------------------------------
__global__ void k_out(const float* __restrict__ hid, const float* __restrict__ W2T,
                      const float* __restrict__ b2, float* __restrict__ out) {
    const int tid = threadIdx.x;
    const int o4  = (tid & 31) * 4;
    const int rs  = tid >> 5;
    const int row = blockIdx.x * 8 + rs;
    const float* hrow = hid + (size_t)row * HIDDEN;
    f32x4 acc = {0.f, 0.f, 0.f, 0.f};
    for (int k0 = 0; k0 < HIDDEN; k0 += 4) {
        f32x4 hv = *(const f32x4*)(hrow + k0);
#pragma unroll
        for (int q = 0; q < 4; ++q) {
            f32x4 wv = *(const f32x4*)(W2T + (size_t)(k0 + q) * OPAD + o4);
            acc += hv[q] * wv;
        }
    }
    if (o4 < OUTPUT) {
        float* op = out + (size_t)row * OUTPUT + o4;
#pragma unroll
        for (int q = 0; q < 4; ++q)
            op[q] = acc[q] + b2[o4 + q];
    }
}

// ---------------------------------------------------------------------------
static inline int pick_split(int mtiles) {
    // target 1024 blocks = 4/CU resident; S must divide 160 and give
    // an EVEN kstep count (unroll-2 loop). 160 excluded (ksteps=1).
    int target = 1024 / (mtiles * 8);
    if (target < 1) target = 1;
    const int divs[11] = {80, 40, 32, 20, 16, 10, 8, 5, 4, 2, 1};
    for (int i = 0; i < 11; ++i)
        if (divs[i] <= target) return divs[i];
    return 1;
}

extern "C" void kernel_launch(void* const* d_in, const int* in_sizes, int n_in,
                              void* d_out, int out_size, void* d_ws, size_t ws_size,
                              hipStream_t stream) {
    (void)in_sizes; (void)n_in; (void)out_size;
    const int*   words = (const int*)d_in[0];
    const float* W1    = (const float*)d_in[1];
    const float* b1    = (const float*)d_in[2];
    const float* W2    = (const float*)d_in[3];
    const float* b2    = (const float*)d_in[4];
    float* out = (float*)d_out;

    // workspace layout
    char* ws = (char*)d_ws;
    size_t off = 0;
    bf16_t* W1b  = (bf16_t*)(ws + off); off += (size_t)HIDDEN * KPAD * sizeof(bf16_t); // 21.0 MB
    float*  hid  = (float*) (ws + off); off += (size_t)BATCH * HIDDEN * sizeof(float); // 16.8 MB
    float*  W2T  = (float*) (ws + off); off += (size_t)HIDDEN * OPAD * sizeof(float);  // 0.5 MB
    bf16_t* histC = (bf16_t*)(ws + off);
    size_t rem = (ws_size > off) ? (ws_size - off) : 0;
    int chunkRows = (int)(rem / ((size_t)KPAD * sizeof(bf16_t)));
    chunkRows = (chunkRows / 128) * 128;
    if (chunkRows > BATCH) chunkRows = BATCH;
    if (chunkRows < 128)   chunkRows = 128;

    k_w1bf16<<<dim3(KPAD / 256, HIDDEN), dim3(256), 0, stream>>>(W1, W1b);
    k_w2t<<<dim3(HIDDEN), dim3(OPAD), 0, stream>>>(W2, W2T);
    k_hidinit<<<dim3(BATCH, HIDDEN / 256), dim3(256), 0, stream>>>(b1, hid);

    for (int r0 = 0; r0 < BATCH; r0 += chunkRows) {
        int rows = BATCH - r0;
        if (rows > chunkRows) rows = chunkRows;
        k_hist<<<dim3(rows), dim3(256), 0, stream>>>(words, histC, r0);
        int mtiles = rows / 128;
        int S = pick_split(mtiles);
        int ksteps = (KPAD / 64) / S;
        k_gemm<<<dim3(mtiles, HIDDEN / 128, S), dim3(256), 0, stream>>>(
            histC, W1b, hid + (size_t)r0 * HIDDEN, ksteps);
    }

    k_out<<<dim3(BATCH / 8), dim3(256), 0, stream>>>(hid, W2T, b2, out);
}

// Round 5
// 357.469 us; speedup vs baseline: 2.0325x; 2.0325x over previous
//
#include <hip/hip_runtime.h>
#include <stdint.h>

// Problem constants (fixed by the reference)
#define CHARS   10000
#define KPAD    10240   // K padded to multiple of 64
#define HIDDEN  1024
#define OUTPUT  100
#define OPAD    128     // padded output cols for coalesced W2T
#define BATCH   4096
#define MAXLEN  2048

typedef __bf16 bf16_t;
typedef __bf16 bf16x8 __attribute__((ext_vector_type(8)));
typedef float  f32x4  __attribute__((ext_vector_type(4)));

// ---------------------------------------------------------------------------
// async global->LDS 16B copy (wave-uniform base + lane*16 dest)
// ---------------------------------------------------------------------------
__device__ __forceinline__ void gload_lds16(const void* g, void* l) {
    __builtin_amdgcn_global_load_lds(
        (const __attribute__((address_space(1))) uint32_t*)g,
        (__attribute__((address_space(3))) uint32_t*)l,
        16, 0, 0);
}

// ---------------------------------------------------------------------------
// W1 (HIDDEN x CHARS fp32) -> W1b (HIDDEN x KPAD bf16), zero-padded cols.
// ---------------------------------------------------------------------------
__global__ void k_w1bf16(const float* __restrict__ W1, bf16_t* __restrict__ W1b) {
    int c = blockIdx.x * 256 + threadIdx.x;   // 0..KPAD-1
    int h = blockIdx.y;                       // 0..HIDDEN-1
    float v = (c < CHARS) ? W1[(size_t)h * CHARS + c] : 0.0f;
    W1b[(size_t)h * KPAD + c] = (bf16_t)v;
}

// ---------------------------------------------------------------------------
// W2 (OUTPUT x HIDDEN fp32) -> W2T (HIDDEN x OPAD fp32), zero-padded cols.
// ---------------------------------------------------------------------------
__global__ void k_w2t(const float* __restrict__ W2, float* __restrict__ W2T) {
    int o = threadIdx.x;      // 0..127
    int k = blockIdx.x;       // 0..1023
    W2T[(size_t)k * OPAD + o] = (o < OUTPUT) ? W2[(size_t)o * HIDDEN + k] : 0.0f;
}

// ---------------------------------------------------------------------------
// hid pre-init with b1 (split-K GEMM atomically accumulates on top)
// ---------------------------------------------------------------------------
__global__ void k_hidinit(const float* __restrict__ b1, float* __restrict__ hid) {
    int h = blockIdx.y * 256 + threadIdx.x;   // 0..1023
    hid[(size_t)blockIdx.x * HIDDEN + h] = b1[h];
}

// ---------------------------------------------------------------------------
// Per-row histogram: one block per batch row. 40KB LDS uint32 counts.
// ---------------------------------------------------------------------------
__global__ void k_hist(const int* __restrict__ words, bf16_t* __restrict__ hist,
                       int rowStart) {
    __shared__ uint32_t h[KPAD];              // 40 KB
    const int tid = threadIdx.x;
    for (int i = tid; i < KPAD; i += 256) h[i] = 0u;
    __syncthreads();
    const int* w = words + (size_t)(rowStart + blockIdx.x) * MAXLEN;
    for (int i = tid; i < MAXLEN; i += 256)
        atomicAdd(&h[w[i]], 1u);
    __syncthreads();
    bf16_t* dst = hist + (size_t)blockIdx.x * KPAD;
    for (int i = tid; i < KPAD; i += 256)
        dst[i] = (bf16_t)(float)h[i];
}

// ---------------------------------------------------------------------------
// compute one BK=64 k-step from an LDS buffer pair (XOR-swizzled layout:
// LDS chunk c of row r holds global 16B-chunk c^(r&7); conflict-free, R2).
// ---------------------------------------------------------------------------
__device__ __forceinline__ void compute_step(const bf16_t* As, const bf16_t* Bs,
                                             int wm, int wn, int fr, int qd,
                                             f32x4 acc[4][4]) {
#pragma unroll
    for (int kk = 0; kk < 64; kk += 32) {
        const int gc = (kk >> 3) + qd;        // global 16B-chunk index 0..7
        bf16x8 af[4], bq[4];
#pragma unroll
        for (int i = 0; i < 4; ++i) {
            const int R = wm + i * 16 + fr;
            af[i] = *(const bf16x8*)(As + R * 64 + ((gc ^ (R & 7)) * 8));
        }
#pragma unroll
        for (int j = 0; j < 4; ++j) {
            const int R = wn + j * 16 + fr;
            bq[j] = *(const bf16x8*)(Bs + R * 64 + ((gc ^ (R & 7)) * 8));
        }
#pragma unroll
        for (int i = 0; i < 4; ++i)
#pragma unroll
            for (int j = 0; j < 4; ++j)
                acc[i][j] = __builtin_amdgcn_mfma_f32_16x16x32_bf16(
                    af[i], bq[j], acc[i][j], 0, 0, 0);
    }
}

// ---------------------------------------------------------------------------
// bf16 MFMA GEMM, AITER-style pipeline:
//   128x128 tile, BK=64, 16x16x32 MFMA, global_load_lds width=16 staging
//   into DOUBLE-buffered LDS (64 KB), with hand-rolled
//     s_waitcnt vmcnt(8); s_barrier        (leading: prev buffer landed;
//                                           newest 8 loads stay in flight)
//     s_waitcnt lgkmcnt(0); s_barrier      (trailing: reads drained)
//   so the vmcnt never drains to 0 in steady state — each buffer's loads
//   get a full compute phase of latency cover.
//   Split-K over blockIdx.z -> fp32 atomicAdd into pre-initialized hid.
// ---------------------------------------------------------------------------
__global__ void __launch_bounds__(256)
k_gemm(const bf16_t* __restrict__ A, const bf16_t* __restrict__ Bt,
       float* __restrict__ hid, int ksteps_per_slice) {
    __shared__ __attribute__((aligned(16))) bf16_t As[2][128 * 64];  // 2x16 KB
    __shared__ __attribute__((aligned(16))) bf16_t Bs[2][128 * 64];  // 2x16 KB

    const int tid  = threadIdx.x;
    const int lane = tid & 63;
    const int wave = tid >> 6;
    const int m0 = blockIdx.x * 128;
    const int n0 = blockIdx.y * 128;
    const long kbeg = (long)blockIdx.z * ksteps_per_slice * 64;
    const long kend = kbeg + (long)ksteps_per_slice * 64;

    // staging: thread covers rows srow+32i (i=0..3); source = global chunk
    // (tid&7)^(srow&7); dest forced to base + tid*16  => LDS(r,c) = g-chunk
    // c^(r&7). Conflict-free for both write and read (R2: measured 0).
    const int srow = tid >> 3;                       // 0..31
    const int gch  = (tid & 7) ^ (srow & 7);
    const bf16_t* Ag = A  + (size_t)(m0 + srow) * KPAD + gch * 8;
    const bf16_t* Bg = Bt + (size_t)(n0 + srow) * KPAD + gch * 8;

    f32x4 acc[4][4] = {};
    const int wm = (wave & 1) * 64;       // wave's 64x64 sub-tile
    const int wn = (wave >> 1) * 64;
    const int fr = lane & 15;
    const int qd = lane >> 4;

    // prologue: fill buffer 0 with k-step kbeg (8 loads in flight)
#pragma unroll
    for (int i = 0; i < 4; ++i) {
        gload_lds16(Ag + (size_t)i * 32 * KPAD + kbeg, As[0] + i * 2048 + tid * 8);
        gload_lds16(Bg + (size_t)i * 32 * KPAD + kbeg, Bs[0] + i * 2048 + tid * 8);
    }

    int buf = 0;
    for (long k = kbeg; k < kend; k += 64) {
        // prefetch next k-step into the other buffer (wrap on final step so
        // the vmcnt(8) bookkeeping stays invariant; wrapped data is unused)
        const long kn = (k + 64 < kend) ? (k + 64) : kbeg;
        const int nb = buf ^ 1;
#pragma unroll
        for (int i = 0; i < 4; ++i) {
            gload_lds16(Ag + (size_t)i * 32 * KPAD + kn, As[nb] + i * 2048 + tid * 8);
            gload_lds16(Bg + (size_t)i * 32 * KPAD + kn, Bs[nb] + i * 2048 + tid * 8);
        }
        // wait: all but the 8 just-issued loads have landed (i.e. buf ready)
        asm volatile("s_waitcnt vmcnt(8)\n\ts_barrier" ::: "memory");
        compute_step(As[buf], Bs[buf], wm, wn, fr, qd, acc);
        // reads drained before anyone overwrites this buffer next iter
        asm volatile("s_waitcnt lgkmcnt(0)\n\ts_barrier" ::: "memory");
        buf = nb;
    }

    // epilogue: C/D layout col=lane&15, row=(lane>>4)*4+reg  [guide §3, m89]
    const int er = (lane >> 4) * 4;
    const int ec = lane & 15;
#pragma unroll
    for (int i = 0; i < 4; ++i) {
#pragma unroll
        for (int j = 0; j < 4; ++j) {
            float* dst = hid + (size_t)(m0 + wm + i * 16 + er) * HIDDEN
                             + (n0 + wn + j * 16 + ec);
#pragma unroll
            for (int r = 0; r < 4; ++r)
                atomicAdd(dst + (size_t)r * HIDDEN, acc[i][j][r]);
        }
    }
}

// ---------------------------------------------------------------------------
// out[b,o] = sum_k hid[b,k] * W2T[k,o] + b2[o]
// ---------------------------------------------------------------------------
__global__ void k_out(const float* __restrict__ hid, const float* __restrict__ W2T,
                      const float* __restrict__ b2, float* __restrict__ out) {
    const int tid = threadIdx.x;
    const int o4  = (tid & 31) * 4;
    const int rs  = tid >> 5;
    const int row = blockIdx.x * 8 + rs;
    const float* hrow = hid + (size_t)row * HIDDEN;
    f32x4 acc = {0.f, 0.f, 0.f, 0.f};
    for (int k0 = 0; k0 < HIDDEN; k0 += 4) {
        f32x4 hv = *(const f32x4*)(hrow + k0);
#pragma unroll
        for (int q = 0; q < 4; ++q) {
            f32x4 wv = *(const f32x4*)(W2T + (size_t)(k0 + q) * OPAD + o4);
            acc += hv[q] * wv;
        }
    }
    if (o4 < OUTPUT) {
        float* op = out + (size_t)row * OUTPUT + o4;
#pragma unroll
        for (int q = 0; q < 4; ++q)
            op[q] = acc[q] + b2[o4 + q];
    }
}

// ---------------------------------------------------------------------------
static inline int pick_split(int mtiles) {
    // target 512 blocks = one full residency round at 2 blocks/CU (64KB LDS);
    // S must divide 160 k-steps
    int target = 512 / (mtiles * 8);
    if (target < 1) target = 1;
    const int divs[12] = {160, 80, 40, 32, 20, 16, 10, 8, 5, 4, 2, 1};
    for (int i = 0; i < 12; ++i)
        if (divs[i] <= target) return divs[i];
    return 1;
}

extern "C" void kernel_launch(void* const* d_in, const int* in_sizes, int n_in,
                              void* d_out, int out_size, void* d_ws, size_t ws_size,
                              hipStream_t stream) {
    (void)in_sizes; (void)n_in; (void)out_size;
    const int*   words = (const int*)d_in[0];
    const float* W1    = (const float*)d_in[1];
    const float* b1    = (const float*)d_in[2];
    const float* W2    = (const float*)d_in[3];
    const float* b2    = (const float*)d_in[4];
    float* out = (float*)d_out;

    // workspace layout
    char* ws = (char*)d_ws;
    size_t off = 0;
    bf16_t* W1b  = (bf16_t*)(ws + off); off += (size_t)HIDDEN * KPAD * sizeof(bf16_t); // 21.0 MB
    float*  hid  = (float*) (ws + off); off += (size_t)BATCH * HIDDEN * sizeof(float); // 16.8 MB
    float*  W2T  = (float*) (ws + off); off += (size_t)HIDDEN * OPAD * sizeof(float);  // 0.5 MB
    bf16_t* histC = (bf16_t*)(ws + off);
    size_t rem = (ws_size > off) ? (ws_size - off) : 0;
    int chunkRows = (int)(rem / ((size_t)KPAD * sizeof(bf16_t)));
    chunkRows = (chunkRows / 128) * 128;
    if (chunkRows > BATCH) chunkRows = BATCH;
    if (chunkRows < 128)   chunkRows = 128;

    k_w1bf16<<<dim3(KPAD / 256, HIDDEN), dim3(256), 0, stream>>>(W1, W1b);
    k_w2t<<<dim3(HIDDEN), dim3(OPAD), 0, stream>>>(W2, W2T);
    k_hidinit<<<dim3(BATCH, HIDDEN / 256), dim3(256), 0, stream>>>(b1, hid);

    for (int r0 = 0; r0 < BATCH; r0 += chunkRows) {
        int rows = BATCH - r0;
        if (rows > chunkRows) rows = chunkRows;
        k_hist<<<dim3(rows), dim3(256), 0, stream>>>(words, histC, r0);
        int mtiles = rows / 128;
        int S = pick_split(mtiles);
        int ksteps = (KPAD / 64) / S;
        k_gemm<<<dim3(mtiles, HIDDEN / 128, S), dim3(256), 0, stream>>>(
            histC, W1b, hid + (size_t)r0 * HIDDEN, ksteps);
    }

    k_out<<<dim3(BATCH / 8), dim3(256), 0, stream>>>(hid, W2T, b2, out);
}